// Round 10
// baseline (149.475 us; speedup 1.0000x reference)
//
#include <hip/hip_runtime.h>
#include <cstdint>

#define B 32
#define D 8732
#define C 21
#define L 32
#define O 8
#define NSEGB 8       // segments (k_mb blocks) per batch
#define SLICE 1092    // ceil(D/8); last slice = 1088
#define NSEG 256      // B * NSEGB
#define NT 1024
#define PAIRB 128     // pairs blocks (2 rows each)
#define TOPB 32
#define FINTGT (PAIRB + TOPB)   // 160

// acc slots (k_mf only): 3 ceN, 4 desk, 5 npp, 6 nnp, 7 tripS, 8 tripC
struct Ws {
  const float *loc, *conf, *line, *pose, *dbox, *targets;
  float* out;
  double* acc;                 // 9 atomic accumulators (zeroed by k_mb blk0)
  int* ictr;                   // [1]=finCtr (zeroed by k_mb blk0)
  int* cnt;                    // NSEG per-seg positive count (uncapped)
  int* posSlice;               // NSEG*256 packed (d | cls<<14 | bi<<19)
  float* sce;                  // B*D mined-ce
  double *gLossL, *gLossP, *gCeP;   // NSEG per-block partials (plain stores)
};

__device__ inline double waveSumD(double v) {
  #pragma unroll
  for (int s = 32; s > 0; s >>= 1) v += __shfl_down(v, s, 64);
  return v;
}

__device__ inline float iou_one(float tx1, float ty1, float tx2, float ty2, float ta,
                                float px1, float py1, float px2, float py2, float areaB) {
  float lx = fmaxf(tx1, px1), ly = fmaxf(ty1, py1);
  float rx = fminf(tx2, px2), ry = fminf(ty2, py2);
  float iw = fmaxf(rx - lx, 0.f), ih = fmaxf(ry - ly, 0.f);
  float inter = iw * ih;
  return inter / (ta + areaB - inter);
}

// ============ K1: fused best-prior + match. 256 blocks x 1024 thr.
// Each block redundantly computes the FULL-D best-prior for its batch
// (block-local, deterministic, zero cross-block protocol), then matches
// its 1092-prior slice. blk0 zeroes acc/finCtr for k_mf (boundary-flushed). ============
struct ShM {
  float tb[O][4], ta[O], tl[O], tp_[O][3];
  unsigned long long wm[16][O];
  int bpd[O];
  int plist[256];
  int wcnt[16], wbase[16];
  double wred[16][3];
  int run;
};

__global__ __launch_bounds__(NT) void k_mb(Ws p) {
  __shared__ ShM sh;
  int g = blockIdx.x, tid = threadIdx.x;
  int lane = tid & 63, wav = tid >> 6;
  int b = g >> 3, s = g & 7;
  int dBeg = s * SLICE;
  int dEnd = dBeg + SLICE; if (dEnd > D) dEnd = D;

  if (g == 0) {
    if (tid < 9) p.acc[tid] = 0.0;
    else if (tid == 9) p.ictr[1] = 0;
  }
  if (tid < O) {
    const float* tr = p.targets + ((size_t)b * O + tid) * 9;
    sh.tb[tid][0] = tr[0]; sh.tb[tid][1] = tr[1];
    sh.tb[tid][2] = tr[2]; sh.tb[tid][3] = tr[3];
    sh.ta[tid] = (tr[2] - tr[0]) * (tr[3] - tr[1]);
    sh.tl[tid] = tr[4];
    sh.tp_[tid][0] = tr[5]; sh.tp_[tid][1] = tr[6]; sh.tp_[tid][2] = tr[7];
  }
  if (tid == 0) sh.run = 0;
  __syncthreads();

  // ---- BP phase: full-D scan, block-local (reuses nothing, needs no one) ----
  {
    float bpv[O]; int bpdl[O];
    #pragma unroll
    for (int t = 0; t < O; t++) { bpv[t] = 0.f; bpdl[t] = 0; }
    for (int d0 = 0; d0 < D; d0 += NT) {
      int d = d0 + tid;
      if (d < D) {
        float4 db = *(const float4*)(p.dbox + (size_t)d * 4);
        float px1 = db.x - 0.5f*db.z, py1 = db.y - 0.5f*db.w;
        float px2 = db.x + 0.5f*db.z, py2 = db.y + 0.5f*db.w;
        float areaB = db.z * db.w;
        #pragma unroll
        for (int t = 0; t < O; t++) {
          float iou = iou_one(sh.tb[t][0], sh.tb[t][1], sh.tb[t][2], sh.tb[t][3],
                              sh.ta[t], px1, py1, px2, py2, areaB);
          if (iou > bpv[t]) { bpv[t] = iou; bpdl[t] = d; }  // ascending d: first max kept
        }
      }
    }
    #pragma unroll
    for (int t = 0; t < O; t++) {
      unsigned long long k = ((unsigned long long)__float_as_uint(bpv[t]) << 32)
                           | (unsigned long long)(0xFFFFFFFFu - (unsigned)bpdl[t]);
      #pragma unroll
      for (int sft = 32; sft > 0; sft >>= 1) {
        unsigned long long o = __shfl_down(k, sft, 64);
        if (o > k) k = o;
      }
      if (lane == 0) sh.wm[wav][t] = k;
    }
    __syncthreads();
    if (tid < O) {
      unsigned long long k = sh.wm[0][tid];
      #pragma unroll
      for (int w = 1; w < 16; w++) if (sh.wm[w][tid] > k) k = sh.wm[w][tid];
      sh.bpd[tid] = (int)(0xFFFFFFFFu - (unsigned)(k & 0xFFFFFFFFull));
    }
    __syncthreads();
  }

  // ---- match phase: 2 chunks over [dBeg, dEnd) ----
  const unsigned long long lt = (lane == 0) ? 0ull : (~0ull >> (64 - lane));
  double ll = 0, lp = 0, cp = 0;
  for (int d0 = dBeg; d0 < dEnd; d0 += NT) {
    int d = d0 + tid;
    bool act = d < dEnd;
    int cls = 0, bi = 0;
    if (act) {
      float4 db = *(const float4*)(p.dbox + (size_t)d * 4);
      float px1 = db.x - 0.5f*db.z, py1 = db.y - 0.5f*db.w;
      float px2 = db.x + 0.5f*db.z, py2 = db.y + 0.5f*db.w;
      float areaB = db.z * db.w;
      float bv = -1.0f;
      #pragma unroll
      for (int t = 0; t < O; t++) {
        float iou = iou_one(sh.tb[t][0], sh.tb[t][1], sh.tb[t][2], sh.tb[t][3],
                            sh.ta[t], px1, py1, px2, py2, areaB);
        if (iou > bv) { bv = iou; bi = t; }     // argmax axis=0: first max wins
      }
      #pragma unroll
      for (int t = O - 1; t >= 0; t--)          // numpy scatter: last truth wins
        if (sh.bpd[t] == d) { bi = t; bv = 2.0f; break; }
      cls = (bv < 0.5f) ? 0 : ((int)sh.tl[bi] + 1);
      const float* cb = p.conf + ((size_t)b * D + d) * C;
      float x[C];
      #pragma unroll
      for (int c = 0; c < C; c++) x[c] = cb[c];
      float m = x[0];
      #pragma unroll
      for (int c = 1; c < C; c++) m = fmaxf(m, x[c]);
      float sm = 0.f;
      #pragma unroll
      for (int c = 0; c < C; c++) sm += __expf(x[c] - m);
      float xc = x[0];
      #pragma unroll
      for (int c = 1; c < C; c++) xc = (cls == c) ? x[c] : xc;
      float ce = m + __logf(sm) - xc;
      size_t bd = (size_t)b * D + d;
      if (cls > 0) {
        cp += ce;
        p.sce[bd] = 0.f;
        float g0 = ((sh.tb[bi][0] + sh.tb[bi][2]) * 0.5f - db.x) / (0.1f * db.z);
        float g1 = ((sh.tb[bi][1] + sh.tb[bi][3]) * 0.5f - db.y) / (0.1f * db.w);
        float g2 = logf((sh.tb[bi][2] - sh.tb[bi][0]) / db.z) / 0.2f;
        float g3 = logf((sh.tb[bi][3] - sh.tb[bi][1]) / db.w) / 0.2f;
        float4 lo = *(const float4*)(p.loc + bd * 4);
        float dv, a;
        dv = lo.x - g0; a = fabsf(dv); ll += (double)((a < 1.f) ? 0.5f*dv*dv : a - 0.5f);
        dv = lo.y - g1; a = fabsf(dv); ll += (double)((a < 1.f) ? 0.5f*dv*dv : a - 0.5f);
        dv = lo.z - g2; a = fabsf(dv); ll += (double)((a < 1.f) ? 0.5f*dv*dv : a - 0.5f);
        dv = lo.w - g3; a = fabsf(dv); ll += (double)((a < 1.f) ? 0.5f*dv*dv : a - 0.5f);
        const float* po = p.pose + bd * 3;
        #pragma unroll
        for (int q = 0; q < 3; q++) {
          float pd = po[q] - sh.tp_[bi][q];
          lp += (double)pd * (double)pd;
        }
      } else {
        p.sce[bd] = fmaxf(ce, 0.f);
      }
    }
    bool pos = act && (cls > 0);
    unsigned long long mm = __ballot(pos);
    if (lane == 0) sh.wcnt[wav] = __popcll(mm);
    __syncthreads();
    if (tid == 0) {
      int r = sh.run;
      #pragma unroll
      for (int w = 0; w < 16; w++) { sh.wbase[w] = r; r += sh.wcnt[w]; }
      sh.run = r;
    }
    __syncthreads();
    if (pos) {
      int rank = sh.wbase[wav] + __popcll(mm & lt);
      if (rank < 256) sh.plist[rank] = d | (cls << 14) | (bi << 19);
    }
    __syncthreads();
  }
  int tot = sh.run;
  if (tid == 0) p.cnt[g] = tot;
  int stored = (tot < 256) ? tot : 256;
  if (tid < stored) p.posSlice[g * 256 + tid] = sh.plist[tid];
  double a0 = waveSumD(ll), a1 = waveSumD(lp), a2 = waveSumD(cp);
  if (lane == 0) { sh.wred[wav][0] = a0; sh.wred[wav][1] = a1; sh.wred[wav][2] = a2; }
  __syncthreads();
  if (tid == 0) {
    double tll = 0, tlp = 0, tcp = 0;
    #pragma unroll
    for (int w = 0; w < 16; w++) { tll += sh.wred[w][0]; tlp += sh.wred[w][1]; tcp += sh.wred[w][2]; }
    p.gLossL[g] = tll; p.gLossP[g] = tlp; p.gCeP[g] = tcp;
  }
}

// ============ K2: blocks 0..127 pairs (2 rows each), 128..159 topk.
// Topk radix: 2 barriers/pass (own-row zero, fused tid<64 select).
// Last arriver BLOCK reduces k_mb's plain partials + acc (R5-validated). ============
struct __align__(16) ShT {
  float sce[D];
  int whist[16][256];
  int scb[NSEGB];
  int nposS;
  unsigned prefixSh; int kkSh;
  double wsum[16], wcnt2[16];
};
struct ShP {
  float embT[L][256];     // transposed: column j = slot j
  float invn[256];
  float qp_s[256][3];
  int   lab_s[256];
  float sd[2][256];
  int   Pi[NSEG + 1];
  int   wscan[4];
  unsigned long long spm[2][4], snm[2][4];
  double w1[2][4];
  int ppc[2][4], npc[2][4];
  double wS[16], wC[16];
};
struct ShD { double lbuf[16]; int last; };
union Sh2 { ShT t; ShP pr; ShD dd; };

__global__ __launch_bounds__(NT) void k_mf(Ws p) {
  __shared__ Sh2 sh;
  int g = blockIdx.x, tid = threadIdx.x;
  int lane = tid & 63, wav = tid >> 6;

  if (g >= PAIRB) {
    // ---------------- top-k (batch bb) ----------------
    int bb = g - PAIRB;
    if (tid < NSEGB) sh.t.scb[tid] = p.cnt[bb * NSEGB + tid];
    const float* ce = p.sce + (size_t)bb * D;
    for (int i = tid; i < D / 4; i += NT)
      ((float4*)sh.t.sce)[i] = ((const float4*)ce)[i];
    __syncthreads();
    if (tid == 0) {
      int np = 0;
      #pragma unroll
      for (int q = 0; q < NSEGB; q++) np += sh.t.scb[q];
      sh.t.nposS = np;
    }
    __syncthreads();
    int npos = sh.t.nposS;
    int k = npos * 3; if (k > D) k = D;
    unsigned prefix = 0; int kk = k;
    for (int pass = 0; pass < 4; pass++) {
      int shift = 24 - 8 * pass;
      // each wave zeroes its OWN whist row (wave-local: no barrier needed)
      for (int i = lane; i < 256; i += 64) sh.t.whist[wav][i] = 0;
      unsigned himask = (pass == 0) ? 0u : (0xFFFFFFFFu << (shift + 8));
      for (int d = tid; d < D; d += NT) {
        unsigned keyb = __float_as_uint(sh.t.sce[d]);
        if ((keyb & himask) == (prefix & himask))
          atomicAdd(&sh.t.whist[wav][(keyb >> shift) & 255], 1);
      }
      __syncthreads();                       // B1: all scans done
      if (tid < 64) {
        int l = tid;
        int h0 = 0, h1 = 0, h2 = 0, h3 = 0;  // fused cross-wave reduce
        #pragma unroll
        for (int w = 0; w < 16; w++) {
          h0 += sh.t.whist[w][l*4+0]; h1 += sh.t.whist[w][l*4+1];
          h2 += sh.t.whist[w][l*4+2]; h3 += sh.t.whist[w][l*4+3];
        }
        int loc4 = h0 + h1 + h2 + h3;
        int suf = loc4;
        #pragma unroll
        for (int st = 1; st < 64; st <<= 1) {
          int o = __shfl_down(suf, st, 64);
          if (l + st < 64) suf += o;
        }
        int snext = suf - loc4;
        int s3 = snext + h3, s2 = s3 + h2, s1 = s2 + h1, s0 = s1 + h0;
        if (s3 >= kk && snext < kk) { sh.t.prefixSh = prefix | ((unsigned)(l*4+3) << shift); sh.t.kkSh = kk - snext; }
        if (s2 >= kk && s3 < kk)    { sh.t.prefixSh = prefix | ((unsigned)(l*4+2) << shift); sh.t.kkSh = kk - s3; }
        if (s1 >= kk && s2 < kk)    { sh.t.prefixSh = prefix | ((unsigned)(l*4+1) << shift); sh.t.kkSh = kk - s2; }
        if (s0 >= kk && s1 < kk)    { sh.t.prefixSh = prefix | ((unsigned)(l*4+0) << shift); sh.t.kkSh = kk - s1; }
      }
      __syncthreads();                       // B2: prefixSh ready; whist reads done
      prefix = sh.t.prefixSh; kk = sh.t.kkSh;
    }
    float T = __uint_as_float(prefix);
    double sgt = 0.0; int cgt = 0;
    for (int d = tid; d < D; d += NT) {
      float v = sh.t.sce[d];
      if (__float_as_uint(v) > prefix) { sgt += (double)v; cgt++; }
    }
    double wv = waveSumD(sgt);
    double wc = waveSumD((double)cgt);
    if (lane == 0) { sh.t.wsum[wav] = wv; sh.t.wcnt2[wav] = wc; }
    __syncthreads();
    if (tid == 0) {
      double tsg = 0, tcg = 0;
      #pragma unroll
      for (int w = 0; w < 16; w++) { tsg += sh.t.wsum[w]; tcg += sh.t.wcnt2[w]; }
      atomicAdd(&p.acc[3], tsg + ((double)k - tcg) * (double)T);
    }
  } else {
    // ---------------- pairs: rows 2g and 2g+1 ----------------
    int rgrp = tid >> 9;            // 0/1 -> row
    int i = 2 * g + rgrp;
    int t5 = tid & 511, j = t5 & 255, qq = t5 >> 8;

    // scan cnt[256] -> Pi
    int v = (tid < NSEG) ? p.cnt[tid] : 0;
    #pragma unroll
    for (int st = 1; st < 64; st <<= 1) {
      int o = __shfl_up(v, st, 64);
      if (lane >= st) v += o;
    }
    if (tid < NSEG && lane == 63) sh.pr.wscan[tid >> 6] = v;
    __syncthreads();
    if (tid < NSEG) {
      int add = 0;
      for (int q = 0; q < (tid >> 6); q++) add += sh.pr.wscan[q];
      sh.pr.Pi[tid + 1] = v + add;
    }
    if (tid == 0) sh.pr.Pi[0] = 0;
    __syncthreads();
    int total = sh.pr.Pi[NSEG];
    int Pc = (total < 256) ? total : 256;

    // gather 256 slots into LDS (shared by both rows)
    if (tid < 256) {
      int slot = tid;
      bool val = slot < Pc;
      int cls = 0, dpr = 0, seg = 0;
      float q0 = 0.f, q1 = 0.f, q2 = 0.f;
      if (val) {
        int lo = 0;
        #pragma unroll
        for (int st = 128; st > 0; st >>= 1) {
          int m = lo + st;
          if (m <= NSEG - 1 && sh.pr.Pi[m] <= slot) lo = m;
        }
        seg = lo;
        int idx = slot - sh.pr.Pi[seg];
        if (idx < 256) {
          int packed = p.posSlice[seg * 256 + idx];
          dpr = packed & 0x3FFF;
          cls = (packed >> 14) & 31;
          int bi = (packed >> 19) & 7;
          int bb2 = seg >> 3;
          const float* tr = p.targets + ((size_t)bb2 * O + bi) * 9;
          q0 = tr[5]; q1 = tr[6]; q2 = tr[7];
        } else val = false;
      }
      float nrm2 = 0.f;
      if (val) {
        int bb2 = seg >> 3;
        const float4* e4 = (const float4*)(p.line + ((size_t)bb2 * D + dpr) * L);
        #pragma unroll
        for (int c = 0; c < 8; c++) {
          float4 t4 = e4[c];
          sh.pr.embT[c*4+0][slot] = t4.x; sh.pr.embT[c*4+1][slot] = t4.y;
          sh.pr.embT[c*4+2][slot] = t4.z; sh.pr.embT[c*4+3][slot] = t4.w;
          nrm2 += t4.x*t4.x + t4.y*t4.y + t4.z*t4.z + t4.w*t4.w;
        }
      } else {
        #pragma unroll
        for (int c = 0; c < L; c++) sh.pr.embT[c][slot] = 0.f;
      }
      sh.pr.invn[slot] = 1.f / fmaxf(sqrtf(nrm2), 1e-12f);
      sh.pr.lab_s[slot] = val ? cls : 0;
      sh.pr.qp_s[slot][0] = q0; sh.pr.qp_s[slot][1] = q1; sh.pr.qp_s[slot][2] = q2;
    }
    __syncthreads();

    int li = sh.pr.lab_s[i];
    bool vi = (i < Pc);
    bool pp = false, np = false;
    double dsk = 0.0;
    if (qq == 0) {
      bool vj = (j < Pc);
      float invi = sh.pr.invn[i], invj = sh.pr.invn[j];
      float sq = 0.f, esq = 0.f;
      #pragma unroll
      for (int c = 0; c < L; c++) {
        float ei = sh.pr.embT[c][i], ej = sh.pr.embT[c][j];
        float dn = ei * invi - ej * invj; sq += dn * dn;
        float de = ei - ej;              esq += de * de;
      }
      float ddv = sqrtf(fmaxf(sq, 1e-12f));
      sh.pr.sd[rgrp][j] = ddv;
      float qsq = 0.f;
      #pragma unroll
      for (int c = 0; c < 3; c++) {
        float dq = sh.pr.qp_s[i][c] - sh.pr.qp_s[j][c];
        qsq += dq * dq;
      }
      bool vp = vi && vj && (i != j);
      bool same = (li == sh.pr.lab_s[j]);
      pp = vp && same && (ddv > 0.2f);
      np = vp && !same && (ddv < 0.8f);
      float diff = esq - qsq;
      dsk = pp ? (double)diff * (double)diff : 0.0;
    }
    unsigned long long pb = __ballot(pp), nb = __ballot(np);
    double dw = waveSumD(dsk);
    if (lane == 0 && qq == 0) {
      int w4 = wav & 3;               // waves 0..3 (row0) / 8..11 (row1)
      sh.pr.spm[rgrp][w4] = pb; sh.pr.snm[rgrp][w4] = nb; sh.pr.w1[rgrp][w4] = dw;
      sh.pr.ppc[rgrp][w4] = (int)__popcll(pb); sh.pr.npc[rgrp][w4] = (int)__popcll(nb);
    }
    __syncthreads();
    unsigned long long pmw = sh.pr.spm[rgrp][j >> 6];
    bool pj = (pmw >> (j & 63)) & 1ull;
    float sdj = sh.pr.sd[rgrp][j];
    double ts = 0.0, tc = 0.0;
    if (pj) {
      for (int it = 0; it < 128; it++) {
        int kx = qq + 2 * it;
        unsigned long long nmw = sh.pr.snm[rgrp][kx >> 6];
        if ((nmw >> (kx & 63)) & 1ull) {
          float xv = sdj - sh.pr.sd[rgrp][kx] + 0.2f;
          if (xv > 0.f) { ts += (double)xv; tc += 1.0; }
        }
      }
    }
    ts = waveSumD(ts); tc = waveSumD(tc);
    if (lane == 0) { sh.pr.wS[wav] = ts; sh.pr.wC[wav] = tc; }
    __syncthreads();
    if (tid == 0) {
      double S = 0, Cc = 0;
      #pragma unroll
      for (int w = 0; w < 16; w++) { S += sh.pr.wS[w]; Cc += sh.pr.wC[w]; }   // both rows
      double dsum = 0; int pcnt = 0, ncnt = 0;
      #pragma unroll
      for (int r = 0; r < 2; r++)
        #pragma unroll
        for (int w = 0; w < 4; w++) {
          dsum += sh.pr.w1[r][w]; pcnt += sh.pr.ppc[r][w]; ncnt += sh.pr.npc[r][w];
        }
      atomicAdd(&p.acc[4], dsum);
      atomicAdd(&p.acc[5], (double)pcnt);
      atomicAdd(&p.acc[6], (double)ncnt);
      atomicAdd(&p.acc[7], S);
      atomicAdd(&p.acc[8], Cc);
    }
  }

  // ---------------- last-arriver block (atomic-only, NO threadfence; R5-validated) ----------------
  __syncthreads();          // all waves done with role's shared memory
  if (tid == 0) {
    asm volatile("s_waitcnt vmcnt(0)" ::: "memory");   // my acc atomics landed
    int prev = __hip_atomic_fetch_add(&p.ictr[1], 1, __ATOMIC_RELAXED, __HIP_MEMORY_SCOPE_AGENT);
    sh.dd.last = (prev == FINTGT - 1);
  }
  __syncthreads();
  if (!sh.dd.last) return;

  // full-block reduce of k_mb's plain partials (cross-boundary: safe)
  auto sumArr = [&](const double* a, int n) -> double {
    double v = 0;
    for (int i2 = tid; i2 < n; i2 += NT) v += a[i2];
    v = waveSumD(v);
    __syncthreads();
    if (lane == 0) sh.dd.lbuf[wav] = v;
    __syncthreads();
    double r = 0;
    #pragma unroll
    for (int w = 0; w < 16; w++) r += sh.dd.lbuf[w];
    __syncthreads();
    return r;
  };
  double lossL = sumArr(p.gLossL, NSEG);
  double lossP = sumArr(p.gLossP, NSEG);
  double ceP   = sumArr(p.gCeP,   NSEG);
  double Ntot;
  {
    double v = 0;
    for (int i2 = tid; i2 < NSEG; i2 += NT) v += (double)p.cnt[i2];
    v = waveSumD(v);
    __syncthreads();
    if (lane == 0) sh.dd.lbuf[wav] = v;
    __syncthreads();
    Ntot = 0;
    #pragma unroll
    for (int w = 0; w < 16; w++) Ntot += sh.dd.lbuf[w];
  }
  if (tid == 0) {
    double ceN   = __hip_atomic_load(&p.acc[3], __ATOMIC_RELAXED, __HIP_MEMORY_SCOPE_AGENT);
    double desk  = __hip_atomic_load(&p.acc[4], __ATOMIC_RELAXED, __HIP_MEMORY_SCOPE_AGENT);
    double npp   = __hip_atomic_load(&p.acc[5], __ATOMIC_RELAXED, __HIP_MEMORY_SCOPE_AGENT);
    double nnp   = __hip_atomic_load(&p.acc[6], __ATOMIC_RELAXED, __HIP_MEMORY_SCOPE_AGENT);
    double tripS = __hip_atomic_load(&p.acc[7], __ATOMIC_RELAXED, __HIP_MEMORY_SCOPE_AGENT);
    double tripC = __hip_atomic_load(&p.acc[8], __ATOMIC_RELAXED, __HIP_MEMORY_SCOPE_AGENT);
    double N = (Ntot > 0.0) ? Ntot : 1.0;
    p.out[0] = (float)(lossL / N);
    p.out[1] = (float)((ceP + ceN) / N);
    p.out[2] = (float)(lossP / N);
    double cnt = (tripC > 0.0) ? tripC : 1.0;
    double loss_t = tripS / cnt;
    double nppd = (npp > 0.0) ? npp : 1.0;
    double tot = npp + nnp;
    double denom = (tot > 0.0) ? tot : 1.0;
    double Ldesk = desk / nppd + loss_t / denom;
    Ldesk = Ldesk / nppd / 32.0;
    p.out[3] = (float)Ldesk;
    p.out[4] = (float)loss_t;
  }
}

extern "C" void kernel_launch(void* const* d_in, const int* in_sizes, int n_in,
                              void* d_out, int out_size, void* d_ws, size_t ws_size,
                              hipStream_t stream) {
  char* ws = (char*)d_ws;
  size_t off = 0;
  auto alloc = [&](size_t bytes) -> char* {
    char* q = ws + off;
    off += (bytes + 255) & ~(size_t)255;
    return q;
  };
  Ws p;
  p.loc     = (const float*)d_in[0];
  p.conf    = (const float*)d_in[1];
  p.line    = (const float*)d_in[2];
  p.pose    = (const float*)d_in[3];
  p.dbox    = (const float*)d_in[4];
  p.targets = (const float*)d_in[5];
  p.out     = (float*)d_out;
  p.acc      = (double*)alloc(16 * 8);
  p.ictr     = (int*)alloc(256);
  p.cnt      = (int*)alloc(NSEG * 4);
  p.posSlice = (int*)alloc((size_t)NSEG * 256 * 4);
  p.sce      = (float*)alloc((size_t)B * D * 4);
  p.gLossL   = (double*)alloc(NSEG * 8);
  p.gLossP   = (double*)alloc(NSEG * 8);
  p.gCeP     = (double*)alloc(NSEG * 8);

  k_mb<<<NSEG,  NT, 0, stream>>>(p);
  k_mf<<<FINTGT, NT, 0, stream>>>(p);
}